// Round 1
// baseline (374.328 us; speedup 1.0000x reference)
//
#include <hip/hip_runtime.h>
#include <hip/hip_bf16.h>

// Problem: B=4, S=2048, C=1024 attention block, fp32 in/out.
// Strategy: fp16 MFMA (16x16x32) GEMMs with fp32 accumulate, m97-style
// 128x128 tile + global_load_lds(16B) staging. Softmax in fp32.

typedef _Float16 half8 __attribute__((ext_vector_type(8)));
typedef _Float16 half4v __attribute__((ext_vector_type(4)));
typedef float f32x4 __attribute__((ext_vector_type(4)));

#define AS1(p) ((const __attribute__((address_space(1))) void*)(p))
#define AS3(p) ((__attribute__((address_space(3))) void*)(p))

// ---------------- fp32 -> fp16 convert (vectorized, n % 2048 == 0) ----------
__global__ __launch_bounds__(256) void cvt_f32_f16(const float* __restrict__ src,
                                                   _Float16* __restrict__ dst, int n) {
    int i = (blockIdx.x * 256 + threadIdx.x) * 8;
    if (i >= n) return;
    float4 a = *(const float4*)(src + i);
    float4 b = *(const float4*)(src + i + 4);
    half8 h;
    h[0] = (_Float16)a.x; h[1] = (_Float16)a.y; h[2] = (_Float16)a.z; h[3] = (_Float16)a.w;
    h[4] = (_Float16)b.x; h[5] = (_Float16)b.y; h[6] = (_Float16)b.z; h[7] = (_Float16)b.w;
    *(half8*)(dst + i) = h;
}

// ---------------- NT GEMM: C[m,n] = scale * sum_k A[m,k]*Bt[n,k] (+bias[n]) --
// 128x128 tile, BK=32, 4 waves, each wave 64x64 via 4x4 grid of 16x16x32 MFMA.
template <int K, bool BIAS, bool F16OUT>
__global__ __launch_bounds__(256, 2)
void gemm_nt(const _Float16* __restrict__ A, const _Float16* __restrict__ Bt,
             const float* __restrict__ bias, void* __restrict__ Cout,
             int M, int N, float scale, long sA, long sB, long sC) {
    __shared__ _Float16 Asm[128 * 32] __attribute__((aligned(16)));
    __shared__ _Float16 Bsm[128 * 32] __attribute__((aligned(16)));
    const int tid = threadIdx.x;
    const int lane = tid & 63;
    const int wave = tid >> 6;
    const long zb = blockIdx.z;
    A += zb * sA;
    Bt += zb * sB;
    const int m0 = blockIdx.y * 128;
    const int n0 = blockIdx.x * 128;
    const int srow = lane >> 2;          // 0..15  (staging row within 16-row slab)
    const int scol = (lane & 3) << 3;    // 0,8,16,24 halves (16B chunks)
    const int quad = lane >> 4;          // 0..3
    const int l16 = lane & 15;
    const int wm = (wave >> 1) << 6;     // 0 or 64
    const int wn = (wave & 1) << 6;      // 0 or 64

    f32x4 acc[4][4];
#pragma unroll
    for (int i = 0; i < 4; i++)
#pragma unroll
        for (int j = 0; j < 4; j++)
#pragma unroll
            for (int r = 0; r < 4; r++) acc[i][j][r] = 0.0f;

    const _Float16* Abase = A + (long)m0 * K;
    const _Float16* Bbase = Bt + (long)n0 * K;

    for (int k0 = 0; k0 < K; k0 += 32) {
        __syncthreads();  // previous iteration's LDS reads complete
#pragma unroll
        for (int t = 0; t < 2; ++t) {
            const int rbase = wave * 16 + t * 64;  // wave-uniform
            __builtin_amdgcn_global_load_lds(
                AS1(Abase + (long)(rbase + srow) * K + k0 + scol),
                AS3(Asm + rbase * 32), 16, 0, 0);
            __builtin_amdgcn_global_load_lds(
                AS1(Bbase + (long)(rbase + srow) * K + k0 + scol),
                AS3(Bsm + rbase * 32), 16, 0, 0);
        }
        __syncthreads();  // staging drained (compiler emits vmcnt(0) before barrier)

        half8 af[4], bf[4];
#pragma unroll
        for (int i = 0; i < 4; i++)
            af[i] = *(const half8*)(Asm + (wm + i * 16 + l16) * 32 + quad * 8);
#pragma unroll
        for (int j = 0; j < 4; j++)
            bf[j] = *(const half8*)(Bsm + (wn + j * 16 + l16) * 32 + quad * 8);
#pragma unroll
        for (int i = 0; i < 4; i++)
#pragma unroll
            for (int j = 0; j < 4; j++)
                acc[i][j] = __builtin_amdgcn_mfma_f32_16x16x32_f16(af[i], bf[j], acc[i][j], 0, 0, 0);
    }

    // Epilogue: C/D layout col=lane&15, row=quad*4+reg (m89/m121-128 verified).
#pragma unroll
    for (int i = 0; i < 4; i++) {
        const int row = m0 + wm + i * 16 + quad * 4;
#pragma unroll
        for (int j = 0; j < 4; j++) {
            const int col = n0 + wn + j * 16 + l16;
            const float badd = BIAS ? bias[col] : 0.0f;
#pragma unroll
            for (int r = 0; r < 4; r++) {
                float v = acc[i][j][r] * scale + badd;
                if constexpr (F16OUT) {
                    ((_Float16*)Cout + zb * sC)[(long)(row + r) * N + col] = (_Float16)v;
                } else {
                    ((float*)Cout + zb * sC)[(long)(row + r) * N + col] = v;
                }
            }
        }
    }
}

// ---------------- fp16 transpose: dst[c][r] = src[r][c], 64x64 LDS tiles -----
__global__ __launch_bounds__(256) void transpose_f16(const _Float16* __restrict__ src,
                                                     _Float16* __restrict__ dst,
                                                     int rows, int cols) {
    __shared__ _Float16 tile[64 * 72] __attribute__((aligned(16)));
    const long b = blockIdx.z;
    src += b * (long)rows * cols;
    dst += b * (long)rows * cols;
    const int r0 = blockIdx.y * 64;
    const int c0 = blockIdx.x * 64;
    const int t = threadIdx.x;
#pragma unroll
    for (int it = 0; it < 2; ++it) {
        int c = t + it * 256;
        int rr = c >> 3;
        int cc = (c & 7) << 3;
        *(half8*)&tile[rr * 72 + cc] = *(const half8*)&src[(long)(r0 + rr) * cols + c0 + cc];
    }
    __syncthreads();
#pragma unroll
    for (int it = 0; it < 2; ++it) {
        int c = t + it * 256;
        int d = c >> 3;            // dst row within tile (original col)
        int kc = (c & 7) << 3;     // dst col chunk (original row)
        half8 h;
#pragma unroll
        for (int j = 0; j < 8; j++) h[j] = tile[(kc + j) * 72 + d];
        *(half8*)&dst[(long)(c0 + d) * rows + r0 + kc] = h;
    }
}

// ---------------- row softmax: fp32 scores [8192][2048] -> fp16 probs --------
__global__ __launch_bounds__(256) void softmax_f32_f16(const float* __restrict__ S,
                                                       _Float16* __restrict__ P) {
    const long row = blockIdx.x;
    const float4* s = (const float4*)(S + row * 2048);
    const int t = threadIdx.x;
    const int wave = t >> 6, lane = t & 63;
    float4 a = s[t];
    float4 b = s[t + 256];
    float m = fmaxf(fmaxf(fmaxf(a.x, a.y), fmaxf(a.z, a.w)),
                    fmaxf(fmaxf(b.x, b.y), fmaxf(b.z, b.w)));
#pragma unroll
    for (int off = 32; off > 0; off >>= 1) m = fmaxf(m, __shfl_xor(m, off, 64));
    __shared__ float redm[4], reds[4];
    if (lane == 0) redm[wave] = m;
    __syncthreads();
    m = fmaxf(fmaxf(redm[0], redm[1]), fmaxf(redm[2], redm[3]));
    float e0 = __expf(a.x - m), e1 = __expf(a.y - m), e2 = __expf(a.z - m), e3 = __expf(a.w - m);
    float e4 = __expf(b.x - m), e5 = __expf(b.y - m), e6 = __expf(b.z - m), e7 = __expf(b.w - m);
    float sum = ((e0 + e1) + (e2 + e3)) + ((e4 + e5) + (e6 + e7));
#pragma unroll
    for (int off = 32; off > 0; off >>= 1) sum += __shfl_xor(sum, off, 64);
    if (lane == 0) reds[wave] = sum;
    __syncthreads();
    sum = (reds[0] + reds[1]) + (reds[2] + reds[3]);
    const float inv = 1.0f / sum;
    half4v h0, h1;
    h0[0] = (_Float16)(e0 * inv); h0[1] = (_Float16)(e1 * inv);
    h0[2] = (_Float16)(e2 * inv); h0[3] = (_Float16)(e3 * inv);
    h1[0] = (_Float16)(e4 * inv); h1[1] = (_Float16)(e5 * inv);
    h1[2] = (_Float16)(e6 * inv); h1[3] = (_Float16)(e7 * inv);
    ((half4v*)(P + row * 2048))[t] = h0;
    ((half4v*)(P + row * 2048))[t + 256] = h1;
}

// ---------------- launch ----------------------------------------------------
extern "C" void kernel_launch(void* const* d_in, const int* in_sizes, int n_in,
                              void* d_out, int out_size, void* d_ws, size_t ws_size,
                              hipStream_t stream) {
    constexpr int B = 4, S = 2048, C = 1024;
    constexpr long XSZ = (long)B * S * C;   // 8388608
    constexpr long WSZ = (long)C * C;       // 1048576
    constexpr long SSZ = (long)B * S * S;   // 16777216

    const float* query = (const float*)d_in[0];
    const float* key   = (const float*)d_in[1];
    const float* value = (const float*)d_in[2];
    const float* Wq = (const float*)d_in[3];
    const float* bq = (const float*)d_in[4];
    const float* Wk = (const float*)d_in[5];
    const float* bk = (const float*)d_in[6];
    const float* Wv = (const float*)d_in[7];
    const float* bv = (const float*)d_in[8];
    float* out = (float*)d_out;
    char* ws = (char*)d_ws;

    // Overlapped workspace layout (bytes). Region0 [0, 73400320): Xq,Xk,Xv,Wq,Wk,Wv,Vh
    // (all dead after transpose) -> reused for fp32 scores (67108864 B).
    // Region1 [73400320): Qh,Kh (dead after QK^T) -> reused for fp16 attn (same size).
    // Region2 [106954752): Vt.  Total 123731968 B.
    _Float16* Xq  = (_Float16*)(ws + 0);
    _Float16* Xk  = (_Float16*)(ws + XSZ * 2);
    _Float16* Xv  = (_Float16*)(ws + 2 * XSZ * 2);
    _Float16* Wqh = (_Float16*)(ws + 3 * XSZ * 2);
    _Float16* Wkh = (_Float16*)(ws + 3 * XSZ * 2 + WSZ * 2);
    _Float16* Wvh = (_Float16*)(ws + 3 * XSZ * 2 + 2 * WSZ * 2);
    _Float16* Vh  = (_Float16*)(ws + 3 * XSZ * 2 + 3 * WSZ * 2);
    float*    scores = (float*)(ws + 0);
    _Float16* Qh  = (_Float16*)(ws + 73400320);
    _Float16* Kh  = (_Float16*)(ws + 73400320 + XSZ * 2);
    _Float16* attn = (_Float16*)(ws + 73400320);
    _Float16* Vt  = (_Float16*)(ws + 106954752);
    if (ws_size < 123731968) return;  // fail clean rather than corrupt

    // 1) convert inputs + weights to fp16
    cvt_f32_f16<<<XSZ / 2048, 256, 0, stream>>>(query, Xq, (int)XSZ);
    cvt_f32_f16<<<XSZ / 2048, 256, 0, stream>>>(key,   Xk, (int)XSZ);
    cvt_f32_f16<<<XSZ / 2048, 256, 0, stream>>>(value, Xv, (int)XSZ);
    cvt_f32_f16<<<WSZ / 2048, 256, 0, stream>>>(Wq, Wqh, (int)WSZ);
    cvt_f32_f16<<<WSZ / 2048, 256, 0, stream>>>(Wk, Wkh, (int)WSZ);
    cvt_f32_f16<<<WSZ / 2048, 256, 0, stream>>>(Wv, Wvh, (int)WSZ);

    // 2) projections: Qh = Xq @ Wq^T + bq  (M=8192, N=1024, K=1024), fp16 out
    dim3 gproj(C / 128, (B * S) / 128, 1);
    gemm_nt<1024, true, true><<<gproj, 256, 0, stream>>>(Xq, Wqh, bq, Qh, B * S, C, 1.0f, 0, 0, 0);
    gemm_nt<1024, true, true><<<gproj, 256, 0, stream>>>(Xk, Wkh, bk, Kh, B * S, C, 1.0f, 0, 0, 0);
    gemm_nt<1024, true, true><<<gproj, 256, 0, stream>>>(Xv, Wvh, bv, Vh, B * S, C, 1.0f, 0, 0, 0);

    // 3) Vt[b][d][k] = Vh[b][k][d]  (per batch 2048x1024 -> 1024x2048)
    dim3 gtr(C / 64, S / 64, B);
    transpose_f16<<<gtr, 256, 0, stream>>>(Vh, Vt, S, C);

    // 4) scores = Qh @ Kh^T / 32  (per batch M=N=2048, K=1024), fp32 out
    dim3 gsc(S / 128, S / 128, B);
    gemm_nt<1024, false, false><<<gsc, 256, 0, stream>>>(
        Qh, Kh, nullptr, scores, S, S, 0.03125f, (long)S * C, (long)S * C, (long)S * S);

    // 5) row softmax -> fp16 attn
    softmax_f32_f16<<<B * S, 256, 0, stream>>>(scores, attn);

    // 6) out = attn @ Vt^T  (per batch M=2048, N=1024, K=2048), fp32 out
    dim3 gout(C / 128, S / 128, B);
    gemm_nt<2048, false, false><<<gout, 256, 0, stream>>>(
        attn, Vt, nullptr, out, S, C, 1.0f, (long)S * S, (long)C * S, (long)S * C);
}

// Round 2
// 336.889 us; speedup vs baseline: 1.1111x; 1.1111x over previous
//
#include <hip/hip_runtime.h>
#include <hip/hip_bf16.h>

// B=4, S=2048, C=1024 attention block, fp32 in/out.
// fp16 MFMA (16x16x32) GEMMs, fp32 accumulate, 128x128 tile,
// global_load_lds(16B) staging with XOR bank swizzle, XCD-aware block remap.

typedef _Float16 half8 __attribute__((ext_vector_type(8)));
typedef float f32x4 __attribute__((ext_vector_type(4)));

#define AS1(p) ((const __attribute__((address_space(1))) void*)(p))
#define AS3(p) ((__attribute__((address_space(3))) void*)(p))

// ---------------- fp32 -> fp16 convert, 3 tensors per launch ----------------
__global__ __launch_bounds__(256) void cvt3_f32_f16(
    const float* __restrict__ s0, const float* __restrict__ s1,
    const float* __restrict__ s2, _Float16* __restrict__ d0,
    _Float16* __restrict__ d1, _Float16* __restrict__ d2, int n) {
    const float* s = blockIdx.y == 0 ? s0 : blockIdx.y == 1 ? s1 : s2;
    _Float16* d = blockIdx.y == 0 ? d0 : blockIdx.y == 1 ? d1 : d2;
    int i = (blockIdx.x * 256 + threadIdx.x) * 8;
    if (i >= n) return;
    float4 a = *(const float4*)(s + i);
    float4 b = *(const float4*)(s + i + 4);
    half8 h;
    h[0] = (_Float16)a.x; h[1] = (_Float16)a.y; h[2] = (_Float16)a.z; h[3] = (_Float16)a.w;
    h[4] = (_Float16)b.x; h[5] = (_Float16)b.y; h[6] = (_Float16)b.z; h[7] = (_Float16)b.w;
    *(half8*)(d + i) = h;
}

// ---------------- NT GEMM: C[m,n] = scale*sum_k A[m,k]*Bt[n,k] (+bias[n]) ----
// 128x128 tile, BK=32, 4 waves, wave = 64x64 via 4x4 of 16x16x32 f16 MFMA.
// LDS tiles [128][32] halves with XOR chunk swizzle: global 16B-chunk c of row
// r is stored at chunk position c ^ ((r>>1)&3)  -> 2-way (free) bank access.
// Block remap: lin-id -> xcd = lin&7; each XCD owns contiguous (z,y) rows.
template <int K, bool BIAS, bool F16OUT, int GXS, int GYS, int R>
__global__ __launch_bounds__(256, 2)
void gemm_nt(const _Float16* __restrict__ A, const _Float16* __restrict__ Bt,
             const float* __restrict__ bias, void* __restrict__ Cout,
             int N, float scale, long sA, long sB, long sC) {
    __shared__ _Float16 Asm[128 * 32] __attribute__((aligned(16)));
    __shared__ _Float16 Bsm[128 * 32] __attribute__((aligned(16)));
    const int tid = threadIdx.x;
    const int lane = tid & 63;
    const int wave = tid >> 6;

    // XCD-aware remap of the 1-D block index.
    const int lin = blockIdx.x;
    const int g = lin & 7;
    const int s = lin >> 3;
    const int xt = s & ((1 << GXS) - 1);
    const int row_id = g * R + (s >> GXS);
    const int yt = row_id & ((1 << GYS) - 1);
    const long zb = row_id >> GYS;
    const int m0 = yt * 128;
    const int n0 = xt * 128;

    A += zb * sA;
    Bt += zb * sB;

    const int srow = lane >> 2;                                    // 0..15
    const int csw = (((lane & 3) ^ ((srow >> 1) & 3)) << 3);       // swizzled global chunk (halves)
    const int quad = lane >> 4;                                    // 0..3
    const int l16 = lane & 15;
    const int aswz = ((quad ^ ((l16 >> 1) & 3)) << 3);             // read-side swizzle (halves)
    const int wm = (wave >> 1) << 6;
    const int wn = (wave & 1) << 6;

    f32x4 acc[4][4];
#pragma unroll
    for (int i = 0; i < 4; i++)
#pragma unroll
        for (int j = 0; j < 4; j++)
#pragma unroll
            for (int r = 0; r < 4; r++) acc[i][j][r] = 0.0f;

    const _Float16* Abase = A + (long)m0 * K;
    const _Float16* Bbase = Bt + (long)n0 * K;

    for (int k0 = 0; k0 < K; k0 += 32) {
        __syncthreads();  // previous iteration's LDS reads complete
#pragma unroll
        for (int t = 0; t < 2; ++t) {
            const int rbase = wave * 16 + t * 64;  // wave-uniform
            __builtin_amdgcn_global_load_lds(
                AS1(Abase + (long)(rbase + srow) * K + k0 + csw),
                AS3(Asm + rbase * 32), 16, 0, 0);
            __builtin_amdgcn_global_load_lds(
                AS1(Bbase + (long)(rbase + srow) * K + k0 + csw),
                AS3(Bsm + rbase * 32), 16, 0, 0);
        }
        __syncthreads();  // staging drained

        half8 af[4], bf[4];
#pragma unroll
        for (int i = 0; i < 4; i++)
            af[i] = *(const half8*)(Asm + (wm + i * 16 + l16) * 32 + aswz);
#pragma unroll
        for (int j = 0; j < 4; j++)
            bf[j] = *(const half8*)(Bsm + (wn + j * 16 + l16) * 32 + aswz);
#pragma unroll
        for (int i = 0; i < 4; i++)
#pragma unroll
            for (int j = 0; j < 4; j++)
                acc[i][j] = __builtin_amdgcn_mfma_f32_16x16x32_f16(af[i], bf[j], acc[i][j], 0, 0, 0);
    }

    // Epilogue: C/D layout col=lane&15, row=quad*4+reg (m89/m121-128 verified).
#pragma unroll
    for (int i = 0; i < 4; i++) {
        const int row = m0 + wm + i * 16 + quad * 4;
#pragma unroll
        for (int j = 0; j < 4; j++) {
            const int col = n0 + wn + j * 16 + l16;
            const float badd = BIAS ? bias[col] : 0.0f;
#pragma unroll
            for (int r = 0; r < 4; r++) {
                float v = acc[i][j][r] * scale + badd;
                if constexpr (F16OUT) {
                    ((_Float16*)Cout + zb * sC)[(long)(row + r) * N + col] = (_Float16)v;
                } else {
                    ((float*)Cout + zb * sC)[(long)(row + r) * N + col] = v;
                }
            }
        }
    }
}

// ---------------- fp16 transpose: dst[c][r] = src[r][c], 64x64 LDS tiles -----
__global__ __launch_bounds__(256) void transpose_f16(const _Float16* __restrict__ src,
                                                     _Float16* __restrict__ dst,
                                                     int rows, int cols) {
    __shared__ _Float16 tile[64 * 72] __attribute__((aligned(16)));
    const long b = blockIdx.z;
    src += b * (long)rows * cols;
    dst += b * (long)rows * cols;
    const int r0 = blockIdx.y * 64;
    const int c0 = blockIdx.x * 64;
    const int t = threadIdx.x;
#pragma unroll
    for (int it = 0; it < 2; ++it) {
        int c = t + it * 256;
        int rr = c >> 3;
        int cc = (c & 7) << 3;
        *(half8*)&tile[rr * 72 + cc] = *(const half8*)&src[(long)(r0 + rr) * cols + c0 + cc];
    }
    __syncthreads();
#pragma unroll
    for (int it = 0; it < 2; ++it) {
        int c = t + it * 256;
        int d = c >> 3;
        int kc = (c & 7) << 3;
        half8 h;
#pragma unroll
        for (int j = 0; j < 8; j++) h[j] = tile[(kc + j) * 72 + d];
        *(half8*)&dst[(long)(c0 + d) * rows + r0 + kc] = h;
    }
}

// ---------------- row softmax: fp16 scores [8192][2048] -> fp16 probs --------
__global__ __launch_bounds__(256) void softmax_f16(const _Float16* __restrict__ S,
                                                   _Float16* __restrict__ P) {
    const long row = blockIdx.x;
    const int t = threadIdx.x;
    const int wave = t >> 6, lane = t & 63;
    half8 h = ((const half8*)(S + row * 2048))[t];
    float v[8];
#pragma unroll
    for (int j = 0; j < 8; j++) v[j] = (float)h[j];
    float m = v[0];
#pragma unroll
    for (int j = 1; j < 8; j++) m = fmaxf(m, v[j]);
#pragma unroll
    for (int off = 32; off > 0; off >>= 1) m = fmaxf(m, __shfl_xor(m, off, 64));
    __shared__ float redm[4], reds[4];
    if (lane == 0) redm[wave] = m;
    __syncthreads();
    m = fmaxf(fmaxf(redm[0], redm[1]), fmaxf(redm[2], redm[3]));
    float sum = 0.0f;
#pragma unroll
    for (int j = 0; j < 8; j++) { v[j] = __expf(v[j] - m); sum += v[j]; }
#pragma unroll
    for (int off = 32; off > 0; off >>= 1) sum += __shfl_xor(sum, off, 64);
    if (lane == 0) reds[wave] = sum;
    __syncthreads();
    sum = (reds[0] + reds[1]) + (reds[2] + reds[3]);
    const float inv = 1.0f / sum;
    half8 o;
#pragma unroll
    for (int j = 0; j < 8; j++) o[j] = (_Float16)(v[j] * inv);
    ((half8*)(P + row * 2048))[t] = o;
}

// ---------------- launch ----------------------------------------------------
extern "C" void kernel_launch(void* const* d_in, const int* in_sizes, int n_in,
                              void* d_out, int out_size, void* d_ws, size_t ws_size,
                              hipStream_t stream) {
    constexpr int B = 4, S = 2048, C = 1024;
    constexpr long XSZ = (long)B * S * C;   // 8388608
    constexpr long WSZ = (long)C * C;       // 1048576

    const float* query = (const float*)d_in[0];
    const float* key   = (const float*)d_in[1];
    const float* value = (const float*)d_in[2];
    const float* Wq = (const float*)d_in[3];
    const float* bq = (const float*)d_in[4];
    const float* Wk = (const float*)d_in[5];
    const float* bk = (const float*)d_in[6];
    const float* Wv = (const float*)d_in[7];
    const float* bv = (const float*)d_in[8];
    float* out = (float*)d_out;
    char* ws = (char*)d_ws;

    // Workspace (bytes): Region0 [0, 73400320): Xq,Xk,Xv,Wqh,Wkh,Wvh,Vh (dead
    // after transpose) -> reused for fp16 scores (33554432 B).
    // Region1 [73400320): Qh,Kh (dead after QK^T) -> reused for fp16 attn.
    // Region2 [106954752): Vt.  Total 123731968 B.
    _Float16* Xq  = (_Float16*)(ws + 0);
    _Float16* Xk  = (_Float16*)(ws + XSZ * 2);
    _Float16* Xv  = (_Float16*)(ws + 2 * XSZ * 2);
    _Float16* Wqh = (_Float16*)(ws + 3 * XSZ * 2);
    _Float16* Wkh = (_Float16*)(ws + 3 * XSZ * 2 + WSZ * 2);
    _Float16* Wvh = (_Float16*)(ws + 3 * XSZ * 2 + 2 * WSZ * 2);
    _Float16* Vh  = (_Float16*)(ws + 3 * XSZ * 2 + 3 * WSZ * 2);
    _Float16* scores = (_Float16*)(ws + 0);
    _Float16* Qh  = (_Float16*)(ws + 73400320);
    _Float16* Kh  = (_Float16*)(ws + 73400320 + XSZ * 2);
    _Float16* attn = (_Float16*)(ws + 73400320);
    _Float16* Vt  = (_Float16*)(ws + 106954752);
    if (ws_size < 123731968) return;

    // 1) convert inputs + weights to fp16 (2 launches)
    cvt3_f32_f16<<<dim3(XSZ / 2048, 3), 256, 0, stream>>>(query, key, value, Xq, Xk, Xv, (int)XSZ);
    cvt3_f32_f16<<<dim3(WSZ / 2048, 3), 256, 0, stream>>>(Wq, Wk, Wv, Wqh, Wkh, Wvh, (int)WSZ);

    // 2) projections: M=8192 (y=64 tiles), N=1024 (x=8 tiles), K=1024, z=1.
    //    GXS=3, GYS=6, R = (512/8)/8 = 8
    gemm_nt<1024, true, true, 3, 6, 8><<<512, 256, 0, stream>>>(Xq, Wqh, bq, Qh, C, 1.0f, 0, 0, 0);
    gemm_nt<1024, true, true, 3, 6, 8><<<512, 256, 0, stream>>>(Xk, Wkh, bk, Kh, C, 1.0f, 0, 0, 0);
    gemm_nt<1024, true, true, 3, 6, 8><<<512, 256, 0, stream>>>(Xv, Wvh, bv, Vh, C, 1.0f, 0, 0, 0);

    // 3) Vt[b][d][k] = Vh[b][k][d]
    dim3 gtr(C / 64, S / 64, B);
    transpose_f16<<<gtr, 256, 0, stream>>>(Vh, Vt, S, C);

    // 4) scores = Qh @ Kh^T / 32, fp16 out. M=N=2048 (16x16 tiles), z=4.
    //    GXS=4, GYS=4, R = (1024/8)/16 = 8
    gemm_nt<1024, false, true, 4, 4, 8><<<1024, 256, 0, stream>>>(
        Qh, Kh, nullptr, scores, S, 0.03125f, (long)S * C, (long)S * C, (long)S * S);

    // 5) row softmax (fp16 in/out)
    softmax_f16<<<B * S, 256, 0, stream>>>(scores, attn);

    // 6) out = attn @ Vt^T, fp32 out. M=2048 (16 y), N=1024 (8 x), K=2048, z=4.
    //    GXS=3, GYS=4, R = (512/8)/8 = 8
    gemm_nt<2048, false, false, 3, 4, 8><<<512, 256, 0, stream>>>(
        attn, Vt, nullptr, out, C, 1.0f, (long)S * S, (long)C * S, (long)S * C);
}